// Round 7
// baseline (1307.597 us; speedup 1.0000x reference)
//
#include <hip/hip_runtime.h>
#include <hip/hip_bf16.h>

// PoolingAttention: B=64 N=197 C=768 H=12 D=64. fp32 in/out (runtime-detected).
// out = [B*N*C] attention output ++ [B*160] keep_index.
//
// R15: GEMMs rebuilt on the R10 single-buffer loop (proven 85us) with three
// LDS-side levers: (1) per-wave tile 64x96 (BM=128,BN=192, acc[4][6]) raises
// arithmetic intensity vs LDS reads 32->38.4 FLOP/B and MFMA-per-barrier
// 16->24; (2) k-group XOR swizzle (pre-swizzled GLOBAL source + swizzled
// read, linear LDS dest per rule #21): stager lane fetches logical k-chunk
// (l&3)^((l>>3)&3), reader uses quad^((l16>>1)&3) -- spreads the former
// 8-way bank alias evenly (free: folds into constant offsets); (3) LDS cut
// to 25.1 KB (single buffer + multi-pass coalesced epilogue reusing the same
// array) + launch_bounds(256,6) -> 6 blocks/CU for latency hiding.
// gmat reverted to the 768-block (b,h) form. R13 coalesced epilogues kept.

#define BB 64
#define NN 197
#define CC 768
#define HH 12
#define DD 64
#define KEEP 160
#define SCALE_F 0.125f   // 64^-0.5
#define OUT0_ELEMS ((size_t)BB * NN * CC)   // 9,682,944
#define VST 212          // attn LDS row stride (u16)

typedef __attribute__((ext_vector_type(8))) short bf16x8_t;
typedef __attribute__((ext_vector_type(4))) float f32x4_t;

__device__ __forceinline__ float b2f(unsigned short u) {
  union { unsigned u; float f; } cv; cv.u = (unsigned)u << 16; return cv.f;
}
__device__ __forceinline__ unsigned short f2b(float f) {   // RNE, finite
  union { float f; unsigned u; } cv; cv.f = f;
  return (unsigned short)((cv.u + 0x7FFFu + ((cv.u >> 16) & 1u)) >> 16);
}
__device__ __forceinline__ float ldmix(const void* p, size_t i, int f32) {
  return f32 ? ((const float*)p)[i] : b2f(((const unsigned short*)p)[i]);
}
// 8 bf16 from LDS via two b64 reads (rows only 8B-aligned at VST=212)
__device__ __forceinline__ bf16x8_t ld8(const unsigned short* p) {
  short4 a = *(const short4*)p;
  short4 b = *(const short4*)(p + 4);
  bf16x8_t v = {a.x, a.y, a.z, a.w, b.x, b.y, b.z, b.w};
  return v;
}
// async global->LDS, 16B per lane; LDS dest = s + lane*16 (wave-uniform base)
__device__ __forceinline__ void gload16(const unsigned short* g,
                                        unsigned short* s) {
  __builtin_amdgcn_global_load_lds(
      (const __attribute__((address_space(1))) void*)g,
      (__attribute__((address_space(3))) void*)s, 16, 0, 0);
}

// ---------------------------------------------------------------------------
__global__ void detect_kernel(const void* x, int* flag) {
  __shared__ int cnt;
  if (threadIdx.x == 0) cnt = 0;
  __syncthreads();
  const unsigned short* u = (const unsigned short*)x;
  int wild = 0;
  for (int i = threadIdx.x; i < 4096; i += 256) {
    int e = (u[i] >> 7) & 0xFF;
    wild += (e >= 140);
  }
  atomicAdd(&cnt, wild);
  __syncthreads();
  if (threadIdx.x == 0) *flag = (cnt > 100) ? 1 : 0;
}

__global__ void cvt_all(const void* qkv_w, const void* proj_w, const void* proj_b,
                        unsigned short* wb, unsigned short* pw, float* pbf,
                        const int* flag) {
  const int W3 = 3 * CC * CC, W1 = CC * CC;
  int i = blockIdx.x * 256 + threadIdx.x;
  const int f32 = *flag;
  if (i < W3) {
    wb[i] = f32 ? f2b(((const float*)qkv_w)[i]) : ((const unsigned short*)qkv_w)[i];
  } else if (i < W3 + W1) {
    int j = i - W3;
    pw[j] = f32 ? f2b(((const float*)proj_w)[j]) : ((const unsigned short*)proj_w)[j];
  } else if (i < W3 + W1 + CC) {
    int j = i - W3 - W1;
    pbf[j] = ldmix(proj_b, j, f32);
  }
}

__global__ void cvt_x(const void* __restrict__ x, size_t elem_off,
                      unsigned short* __restrict__ xb, int n8,
                      const int* __restrict__ flag) {
  const int i = blockIdx.x * 256 + threadIdx.x;
  if (i >= n8) return;
  const size_t src = elem_off + (size_t)i * 8;
  bf16x8_t v;
  if (*flag) {
    const float* xp = (const float*)x + src;
    float4 u0 = *(const float4*)xp;
    float4 u1 = *(const float4*)(xp + 4);
    v = bf16x8_t{(short)f2b(u0.x), (short)f2b(u0.y), (short)f2b(u0.z),
                 (short)f2b(u0.w), (short)f2b(u1.x), (short)f2b(u1.y),
                 (short)f2b(u1.z), (short)f2b(u1.w)};
  } else {
    v = *(const bf16x8_t*)((const unsigned short*)x + src);
  }
  *(bf16x8_t*)(xb + (size_t)i * 8) = v;
}

// ---------------------------------------------------------------------------
// qkv_gemm: 128x192 MFMA GEMM, per-wave 64x96 (acc[4][6]), single-buffered
// global_load_lds staging with kg XOR-swizzle, LDS-coalesced 2-pass epilogue.
// XCD-grouped 1-D grid (12 col-tiles). LDS 25,088 B -> 6 blocks/CU.
// ---------------------------------------------------------------------------
__global__ __launch_bounds__(256, 6) void qkv_gemm(
    const unsigned short* __restrict__ xb,
    const unsigned short* __restrict__ wb,
    unsigned short* __restrict__ qkvc, int Mc, int bc, int nRow) {
  const int xcd = blockIdx.x & 7;
  const int seq = blockIdx.x >> 3;
  const int colt = seq % 12;
  const int rowt = (seq / 12) * 8 + xcd;
  if (rowt >= nRow) return;
  const int m0 = rowt * 128;
  const int n0 = colt * 192;

  // staging: A [0,4096) u16 (128x32), B [4096,10240) u16 (192x32)
  // epilogue: reuse as C half-tile [64][196] u16 (12544 u16 = 25,088 B)
  __shared__ unsigned short lds[12544];
  const int lane = threadIdx.x & 63;
  const int wave = threadIdx.x >> 6;
  const int l16  = lane & 15;
  const int quad = lane >> 4;
  const int wm = wave >> 1, wn = wave & 1;

  // stager: lane -> slot (row = wave*16+(lane>>2), kgslot = lane&3); the slot
  // must hold logical k-chunk kgslot^((row&15)>>1 &3) = (l&3)^((l>>3)&3).
  const int rS   = wave * 16 + (lane >> 2);
  const int koff = ((lane & 3) ^ ((lane >> 3) & 3)) * 8;
  int grA0 = m0 + rS;       if (grA0 >= Mc) grA0 = Mc - 1;
  int grA1 = m0 + rS + 64;  if (grA1 >= Mc) grA1 = Mc - 1;
  const unsigned short* gA0 = xb + (size_t)grA0 * CC + koff;
  const unsigned short* gA1 = xb + (size_t)grA1 * CC + koff;
  const unsigned short* gB0 = wb + (size_t)(n0 + rS) * CC + koff;
  const unsigned short* gB1 = wb + (size_t)(n0 + rS + 64) * CC + koff;
  const unsigned short* gB2 = wb + (size_t)(n0 + rS + 128) * CC + koff;
  unsigned short* const dA = lds + wave * 512;
  unsigned short* const dB = lds + 4096 + wave * 512;

  // reader: logical k-chunk quad lives at kgslot = quad^((l16>>1)&3)
  const int kgs  = (quad ^ ((l16 >> 1) & 3)) * 8;
  const int aoff = l16 * 32 + kgs;          // + (wm*4+r)*512
  const int boff = 4096 + l16 * 32 + kgs;   // + (wn*6+c)*512

  f32x4_t acc[4][6] = {};
  for (int kt = 0; kt < 24; kt++) {
    __syncthreads();                 // WAR: prev step's frag reads retired
    gload16(gA0, dA); gload16(gA1, dA + 2048);
    gload16(gB0, dB); gload16(gB1, dB + 2048); gload16(gB2, dB + 4096);
    gA0 += 32; gA1 += 32; gB0 += 32; gB1 += 32; gB2 += 32;
    __syncthreads();                 // RAW: compiler drains vmcnt(0)
    bf16x8_t afr[4], bfr[6];
    #pragma unroll
    for (int r = 0; r < 4; r++)
      afr[r] = *(const bf16x8_t*)&lds[(wm * 4 + r) * 512 + aoff];
    #pragma unroll
    for (int c = 0; c < 6; c++)
      bfr[c] = *(const bf16x8_t*)&lds[(wn * 6 + c) * 512 + boff];
    #pragma unroll
    for (int r = 0; r < 4; r++)
      #pragma unroll
      for (int c = 0; c < 6; c++)
        acc[r][c] = __builtin_amdgcn_mfma_f32_16x16x32_bf16(afr[r], bfr[c],
                                                            acc[r][c], 0, 0, 0);
  }
  __syncthreads();   // all frag reads retired before LDS reuse

  // ---- epilogue: 2 passes of 64-row halves through [64][196] u16
  #pragma unroll
  for (int h = 0; h < 2; h++) {
    if (wm == h) {
      #pragma unroll
      for (int c = 0; c < 6; c++)
        #pragma unroll
        for (int r = 0; r < 4; r++)
          #pragma unroll
          for (int i = 0; i < 4; i++)
            lds[(r * 16 + quad * 4 + i) * 196 + wn * 96 + c * 16 + l16] =
                f2b(acc[r][c][i]);
    }
    __syncthreads();
    {
      const int rowl = threadIdx.x >> 2;      // 0..63
      const int m = m0 + h * 64 + rowl;
      if (m < Mc) {
        const int bb2 = m / NN, n = m - bb2 * NN;
        #pragma unroll
        for (int j = 0; j < 3; j++) {
          const int c = (threadIdx.x & 3) * 3 + j;   // 0..11 (16-col chunks)
          const int col = n0 + c * 16;
          const int s = col / CC;
          const int rem = col - s * CC;
          const int hc = rem >> 6, d0 = rem & 63;
          const unsigned short* src = lds + rowl * 196 + c * 16;
          uint2 u0 = *(const uint2*)(src);
          uint2 u1 = *(const uint2*)(src + 4);
          uint2 u2 = *(const uint2*)(src + 8);
          uint2 u3 = *(const uint2*)(src + 12);
          unsigned short* dst =
              qkvc + ((((size_t)s * bc + bb2) * HH + hc) * NN + n) * DD + d0;
          *(uint4*)(dst)     = uint4{u0.x, u0.y, u1.x, u1.y};
          *(uint4*)(dst + 8) = uint4{u2.x, u2.y, u3.x, u3.y};
        }
      }
    }
    __syncthreads();
  }
}

// ---------------------------------------------------------------------------
// proj_gemm: 128x192 MFMA GEMM, same K-loop; 4-pass f32 [32][196] epilogue
// with bias + dual-dtype store. XCD-grouped (4 col-tiles).
// ---------------------------------------------------------------------------
__global__ __launch_bounds__(256, 6) void proj_gemm(
    const unsigned short* __restrict__ Yc,
    const unsigned short* __restrict__ pw,
    const float* __restrict__ pbf,
    void* __restrict__ out, size_t out_off, int Mc, int nRow,
    const int* __restrict__ flag) {
  const int xcd = blockIdx.x & 7;
  const int seq = blockIdx.x >> 3;
  const int colt = seq % 4;
  const int rowt = (seq / 4) * 8 + xcd;
  if (rowt >= nRow) return;
  const int m0 = rowt * 128;
  const int n0 = colt * 192;

  __shared__ unsigned short lds[12544];   // staging 10240 u16; epi [32][196] f32
  const int lane = threadIdx.x & 63;
  const int wave = threadIdx.x >> 6;
  const int l16  = lane & 15;
  const int quad = lane >> 4;
  const int wm = wave >> 1, wn = wave & 1;

  const int rS   = wave * 16 + (lane >> 2);
  const int koff = ((lane & 3) ^ ((lane >> 3) & 3)) * 8;
  int grA0 = m0 + rS;       if (grA0 >= Mc) grA0 = Mc - 1;
  int grA1 = m0 + rS + 64;  if (grA1 >= Mc) grA1 = Mc - 1;
  const unsigned short* gA0 = Yc + (size_t)grA0 * CC + koff;
  const unsigned short* gA1 = Yc + (size_t)grA1 * CC + koff;
  const unsigned short* gB0 = pw + (size_t)(n0 + rS) * CC + koff;
  const unsigned short* gB1 = pw + (size_t)(n0 + rS + 64) * CC + koff;
  const unsigned short* gB2 = pw + (size_t)(n0 + rS + 128) * CC + koff;
  unsigned short* const dA = lds + wave * 512;
  unsigned short* const dB = lds + 4096 + wave * 512;

  const int kgs  = (quad ^ ((l16 >> 1) & 3)) * 8;
  const int aoff = l16 * 32 + kgs;
  const int boff = 4096 + l16 * 32 + kgs;

  f32x4_t acc[4][6] = {};
  for (int kt = 0; kt < 24; kt++) {
    __syncthreads();
    gload16(gA0, dA); gload16(gA1, dA + 2048);
    gload16(gB0, dB); gload16(gB1, dB + 2048); gload16(gB2, dB + 4096);
    gA0 += 32; gA1 += 32; gB0 += 32; gB1 += 32; gB2 += 32;
    __syncthreads();
    bf16x8_t afr[4], bfr[6];
    #pragma unroll
    for (int r = 0; r < 4; r++)
      afr[r] = *(const bf16x8_t*)&lds[(wm * 4 + r) * 512 + aoff];
    #pragma unroll
    for (int c = 0; c < 6; c++)
      bfr[c] = *(const bf16x8_t*)&lds[(wn * 6 + c) * 512 + boff];
    #pragma unroll
    for (int r = 0; r < 4; r++)
      #pragma unroll
      for (int c = 0; c < 6; c++)
        acc[r][c] = __builtin_amdgcn_mfma_f32_16x16x32_bf16(afr[r], bfr[c],
                                                            acc[r][c], 0, 0, 0);
  }
  __syncthreads();

  // ---- epilogue: 4 passes of 32-row quarters, f32 [32][196]
  const int f32o = *flag;
  float* Cf = (float*)lds;
  #pragma unroll
  for (int p = 0; p < 4; p++) {
    if (wm == (p >> 1)) {
      #pragma unroll
      for (int rr = 0; rr < 2; rr++) {
        const int r = (p & 1) * 2 + rr;
        #pragma unroll
        for (int c = 0; c < 6; c++) {
          const float bv = pbf[n0 + wn * 96 + c * 16 + l16];
          #pragma unroll
          for (int i = 0; i < 4; i++)
            Cf[(rr * 16 + quad * 4 + i) * 196 + wn * 96 + c * 16 + l16] =
                acc[r][c][i] + bv;
        }
      }
    }
    __syncthreads();
    {
      const int rowl = threadIdx.x >> 3;            // 0..31
      const int m = m0 + p * 32 + rowl;
      if (m < Mc) {
        const int off = (threadIdx.x & 7) * 24;     // 24 f32 per thread
        const float* src = Cf + rowl * 196 + off;
        const size_t ob = out_off + (size_t)m * CC + n0 + off;
        if (f32o) {
          float* dst = (float*)out + ob;
          #pragma unroll
          for (int j = 0; j < 6; j++) {
            float4 v = {src[j * 4], src[j * 4 + 1], src[j * 4 + 2],
                        src[j * 4 + 3]};
            *(float4*)(dst + j * 4) = v;
          }
        } else {
          unsigned short* dst = (unsigned short*)out + ob;
          #pragma unroll
          for (int j = 0; j < 3; j++) {
            uint4 v;
            v.x = (unsigned)f2b(src[j * 8 + 0]) | ((unsigned)f2b(src[j * 8 + 1]) << 16);
            v.y = (unsigned)f2b(src[j * 8 + 2]) | ((unsigned)f2b(src[j * 8 + 3]) << 16);
            v.z = (unsigned)f2b(src[j * 8 + 4]) | ((unsigned)f2b(src[j * 8 + 5]) << 16);
            v.w = (unsigned)f2b(src[j * 8 + 6]) | ((unsigned)f2b(src[j * 8 + 7]) << 16);
            *(uint4*)(dst + j * 8) = v;
          }
        }
      }
    }
    __syncthreads();
  }
}

// ---------------------------------------------------------------------------
// MFMA attention (unchanged R7/R8 structure).
// ---------------------------------------------------------------------------
__global__ __launch_bounds__(256, 3) void attn_kernel(
    const unsigned short* __restrict__ qkvc, int bc,
    unsigned short* __restrict__ Yc) {
  const int bh = blockIdx.x;
  const int bb = bh / HH;
  const int h  = bh % HH;
  const size_t mat = (size_t)bc * HH * NN * DD;
  const unsigned short* q = qkvc + ((size_t)bb * HH + h) * NN * DD;
  const unsigned short* k = q + mat;
  const unsigned short* v = q + 2 * mat;

  __shared__ unsigned short Vt[DD * VST];
  __shared__ unsigned short Pl[4][16 * VST];

  const int lane = threadIdx.x & 63;
  const int wave = threadIdx.x >> 6;
  const int l16  = lane & 15;
  const int quad = lane >> 4;

  #pragma unroll
  for (int it = 0; it < 53; it++) {
    const int key = it * 4 + wave;
    unsigned short val = (key < NN) ? v[(size_t)key * DD + lane]
                                    : (unsigned short)0;
    Vt[lane * VST + key] = val;
  }
  __syncthreads();

  unsigned short* Pw = &Pl[wave][0];

  for (int it = 0; it < 4; it++) {
    const int si = it * 4 + wave;
    if (si >= 13) break;
    const int q0 = si * 16;

    int qrow = q0 + l16; if (qrow >= NN) qrow = NN - 1;
    const unsigned short* qp = q + (size_t)qrow * DD + quad * 8;
    const bf16x8_t aq0 = *(const bf16x8_t*)qp;
    const bf16x8_t aq1 = *(const bf16x8_t*)(qp + 32);

    f32x4_t sc[13];
    #pragma unroll
    for (int ct = 0; ct < 13; ct++) {
      int key = ct * 16 + l16; if (key >= NN) key = NN - 1;
      const unsigned short* kp = k + (size_t)key * DD + quad * 8;
      const bf16x8_t b0 = *(const bf16x8_t*)kp;
      const bf16x8_t b1 = *(const bf16x8_t*)(kp + 32);
      f32x4_t t = {0.f, 0.f, 0.f, 0.f};
      t = __builtin_amdgcn_mfma_f32_16x16x32_bf16(aq0, b0, t, 0, 0, 0);
      t = __builtin_amdgcn_mfma_f32_16x16x32_bf16(aq1, b1, t, 0, 0, 0);
      sc[ct] = t;
    }

    float inv_l[4];
    #pragma unroll
    for (int i = 0; i < 4; i++) {
      float m = -1e30f;
      #pragma unroll
      for (int ct = 0; ct < 13; ct++)
        if (ct < 12 || l16 < 5) m = fmaxf(m, sc[ct][i] * SCALE_F);
      #pragma unroll
      for (int d = 1; d < 16; d <<= 1) m = fmaxf(m, __shfl_xor(m, d, 64));
      float s = 0.f;
      #pragma unroll
      for (int ct = 0; ct < 13; ct++) {
        const float p = (ct < 12 || l16 < 5) ? __expf(sc[ct][i] * SCALE_F - m)
                                             : 0.f;
        sc[ct][i] = p;
        s += p;
      }
      #pragma unroll
      for (int d = 1; d < 16; d <<= 1) s += __shfl_xor(s, d, 64);
      inv_l[i] = 1.0f / s;
    }

    #pragma unroll
    for (int i = 0; i < 4; i++) {
      const int ro = (quad * 4 + i) * VST;
      #pragma unroll
      for (int ct = 0; ct < 13; ct++)
        Pw[ro + ct * 16 + l16] = f2b(sc[ct][i]);
    }

    f32x4_t oc[4] = {};
    #pragma unroll
    for (int ks = 0; ks < 6; ks++) {
      const bf16x8_t ap = ld8(&Pw[l16 * VST + ks * 32 + quad * 8]);
      #pragma unroll
      for (int dt = 0; dt < 4; dt++) {
        const bf16x8_t bv = ld8(&Vt[(dt * 16 + l16) * VST + ks * 32 + quad * 8]);
        oc[dt] = __builtin_amdgcn_mfma_f32_16x16x32_bf16(ap, bv, oc[dt], 0, 0, 0);
      }
    }
    {
      const bf16x8_t zz = {};
      bf16x8_t ap = zz;
      if (quad < 2) ap = ld8(&Pw[l16 * VST + 192 + quad * 8]);
      #pragma unroll
      for (int dt = 0; dt < 4; dt++) {
        bf16x8_t bv = zz;
        if (quad < 2) bv = ld8(&Vt[(dt * 16 + l16) * VST + 192 + quad * 8]);
        oc[dt] = __builtin_amdgcn_mfma_f32_16x16x32_bf16(ap, bv, oc[dt], 0, 0, 0);
      }
    }

    #pragma unroll
    for (int i = 0; i < 4; i++) {
      const int n = q0 + quad * 4 + i;
      if (n < NN) {
        unsigned short* yp = Yc + ((size_t)bb * NN + n) * CC + h * DD;
        #pragma unroll
        for (int dt = 0; dt < 4; dt++)
          yp[dt * 16 + l16] = f2b(oc[dt][i] * inv_l[i]);
      }
    }
  }
}

// ---------------------------------------------------------------------------
// Top-k path (fp32-exact).
// ---------------------------------------------------------------------------
__global__ __launch_bounds__(256, 4) void qcls_kernel(
    const void* __restrict__ x, const void* __restrict__ qkv_w,
    float* __restrict__ qc, const int* __restrict__ flag) {
  const int idx = blockIdx.x * 4 + (threadIdx.x >> 6);
  if (idx >= BB * CC) return;
  const int b = idx / CC, i = idx - b * CC;
  const int lane = threadIdx.x & 63;
  const int f32 = *flag;
  const size_t xr = (size_t)b * NN * CC;
  const size_t wr = (size_t)i * CC;
  float p = 0.f;
  #pragma unroll
  for (int j = 0; j < 12; j++)
    p += ldmix(x, xr + j * 64 + lane, f32) * ldmix(qkv_w, wr + j * 64 + lane, f32);
  #pragma unroll
  for (int m = 32; m; m >>= 1) p += __shfl_xor(p, m, 64);
  if (lane == 0) qc[(size_t)b * CC + i] = p;
}

// gmat: R10 form — grid (b, h), 768 blocks, 3 cols/thread.
__global__ __launch_bounds__(256, 4) void gmat_kernel(
    const void* __restrict__ qkv_w, const float* __restrict__ qc,
    float* __restrict__ g, const int* __restrict__ flag) {
  const int b = blockIdx.x, h = blockIdx.y;
  const int f32 = *flag;
  __shared__ float qh[DD];
  if (threadIdx.x < DD) qh[threadIdx.x] = qc[(size_t)b * CC + h * DD + threadIdx.x];
  __syncthreads();
  const int c0 = threadIdx.x, c1 = c0 + 256, c2 = c1 + 256;
  float a0 = 0.f, a1 = 0.f, a2 = 0.f;
  for (int d = 0; d < DD; d++) {
    const size_t ro = (size_t)(CC + h * DD + d) * CC;
    const float qv = qh[d];
    a0 += ldmix(qkv_w, ro + c0, f32) * qv;
    a1 += ldmix(qkv_w, ro + c1, f32) * qv;
    a2 += ldmix(qkv_w, ro + c2, f32) * qv;
  }
  float* gb = g + ((size_t)b * HH + h) * CC;
  gb[c0] = a0; gb[c1] = a1; gb[c2] = a2;
}

__global__ __launch_bounds__(256, 4) void score_kernel(
    const void* __restrict__ x, const float* __restrict__ g,
    float* __restrict__ wscore, const int* __restrict__ flag) {
  const int idx = blockIdx.x * 4 + (threadIdx.x >> 6);
  if (idx >= BB * NN) return;
  const int b = idx / NN, n = idx - b * NN;
  const int lane = threadIdx.x & 63;
  const int f32 = *flag;
  const size_t xr = ((size_t)b * NN + n) * CC;
  float xv[12];
  #pragma unroll
  for (int j = 0; j < 12; j++) xv[j] = ldmix(x, xr + j * 64 + lane, f32);
  const float* gb = g + (size_t)b * HH * CC;
  float acc = 0.f;
  #pragma unroll
  for (int h = 0; h < HH; h++) {
    const float* gh = gb + (size_t)h * CC;
    float p = 0.f;
    #pragma unroll
    for (int j = 0; j < 12; j++) p += xv[j] * gh[j * 64 + lane];
    #pragma unroll
    for (int m = 32; m; m >>= 1) p += __shfl_xor(p, m, 64);
    acc += fabsf(p);
  }
  if (lane == 0) wscore[(size_t)b * NN + n] = acc;
}

__global__ __launch_bounds__(256, 4) void rank_kernel(
    const float* __restrict__ wscore, void* __restrict__ out,
    const int* __restrict__ flag) {
  const int b = blockIdx.x;
  const int f32 = *flag;
  __shared__ float wgt[NN];
  __shared__ int   rank[NN];
  if (threadIdx.x < NN) wgt[threadIdx.x] = wscore[(size_t)b * NN + threadIdx.x];
  __syncthreads();
  const int n = threadIdx.x;
  if (n < NN) {
    float wi = wgt[n];
    int rk = 0;
    for (int j = 0; j < NN; j++) {
      float wj = wgt[j];
      rk += (wj > wi) || (wj == wi && j < n);
    }
    rank[n] = rk;
  }
  __syncthreads();
  if (n < NN && rank[n] < KEEP) {
    int pos = 0;
    for (int j = 0; j < n; j++) pos += (rank[j] < KEEP);
    const size_t oi = OUT0_ELEMS + (size_t)b * KEEP + pos;
    if (f32) ((float*)out)[oi] = (float)n;
    else ((unsigned short*)out)[oi] = f2b((float)n);
  }
}

// ---------------------------------------------------------------------------
extern "C" void kernel_launch(void* const* d_in, const int* in_sizes, int n_in,
                              void* d_out, int out_size, void* d_ws, size_t ws_size,
                              hipStream_t stream) {
  const void* x      = d_in[0];
  const void* qkv_w  = d_in[1];
  const void* proj_w = d_in[2];
  const void* proj_b = d_in[3];

  char* wsb = (char*)d_ws;
  int* flag = (int*)wsb;
  unsigned short* wb  = (unsigned short*)(wsb + 256);
  unsigned short* pw  = (unsigned short*)(wsb + 256 + 3538944);
  float* pbf    = (float*)(wsb + 256 + 3538944 + 1179648);
  float* qc     = (float*)(wsb + 256 + 3538944 + 1179648 + 4096);
  float* g      = qc + (size_t)BB * CC;
  float* wscore = g + (size_t)BB * HH * CC;
  const size_t fixed = 256 + 3538944 + 1179648 + 4096 + 196608 + 2359296 + 51200;
  char* chunk = wsb + fixed;

  const size_t per_batch = (size_t)NN * CC * 2
                         + 3ull * HH * NN * DD * 2
                         + (size_t)NN * CC * 2;
  int Bc = BB;
  while (Bc > 1 && fixed + (size_t)Bc * per_batch > ws_size) Bc >>= 1;

  unsigned short* xb   = (unsigned short*)chunk;
  unsigned short* qkvc = xb + (size_t)Bc * NN * CC;
  unsigned short* Yc   = qkvc + 3ull * Bc * HH * NN * DD;

  detect_kernel<<<1, 256, 0, stream>>>(x, flag);
  const int cvt_n = 3 * CC * CC + CC * CC + CC;
  cvt_all<<<(cvt_n + 255) / 256, 256, 0, stream>>>(qkv_w, proj_w, proj_b,
                                                   wb, pw, pbf, flag);

  qcls_kernel<<<(BB * CC + 3) / 4, 256, 0, stream>>>(x, qkv_w, qc, flag);
  gmat_kernel<<<dim3(BB, HH), 256, 0, stream>>>(qkv_w, qc, g, flag);
  score_kernel<<<(BB * NN + 3) / 4, 256, 0, stream>>>(x, g, wscore, flag);
  rank_kernel<<<BB, 256, 0, stream>>>(wscore, d_out, flag);

  const int nChunks = (BB + Bc - 1) / Bc;
  for (int cb = 0; cb < nChunks; cb++) {
    const int b0 = cb * Bc;
    const int bc = (BB - b0 < Bc) ? (BB - b0) : Bc;
    const int Mc = bc * NN;
    const int n8 = Mc * CC / 8;
    cvt_x<<<(n8 + 255) / 256, 256, 0, stream>>>(
        x, (size_t)b0 * NN * CC, xb, n8, flag);
    const int nRowQ = (Mc + 127) / 128;
    const int gridQ = 8 * 12 * ((nRowQ + 7) / 8);
    qkv_gemm<<<gridQ, 256, 0, stream>>>(xb, wb, qkvc, Mc, bc, nRowQ);
    attn_kernel<<<dim3(bc * HH), 256, 0, stream>>>(qkvc, bc, Yc);
    const int gridP = 8 * 4 * ((nRowQ + 7) / 8);
    proj_gemm<<<gridP, 256, 0, stream>>>(
        Yc, pw, pbf, d_out, (size_t)b0 * NN * CC, Mc, nRowQ, flag);
  }
}

// Round 8
// 373.722 us; speedup vs baseline: 3.4989x; 3.4989x over previous
//
#include <hip/hip_runtime.h>
#include <hip/hip_bf16.h>

// PoolingAttention: B=64 N=197 C=768 H=12 D=64. fp32 in/out (runtime-detected).
// out = [B*N*C] attention output ++ [B*160] keep_index.
//
// R16: best-of merge + one safe lever.
//  - GEMMs = R13 exactly (128x128, counted-vmcnt dbuf, launch_bounds(256,4),
//    coalesced LDS-transposed epilogues) PLUS the kg XOR swizzle from R15
//    (numerically verified there): stager fetches logical k-chunk
//    (l&3)^((l>>3)&3) (pre-swizzled GLOBAL src, linear LDS dest); reader uses
//    kgs = quad^((l16>>1)&3). Fragment-read bank aliasing 8-way -> 2-way.
//  - gmat back to the R10 768-block (b,h) form (best-total config).
//  - R15's launch_bounds(256,6)+acc[4][6] spill disaster reverted entirely.

#define BB 64
#define NN 197
#define CC 768
#define HH 12
#define DD 64
#define KEEP 160
#define SCALE_F 0.125f   // 64^-0.5
#define OUT0_ELEMS ((size_t)BB * NN * CC)   // 9,682,944
#define VST 212          // attn LDS row stride (u16)

typedef __attribute__((ext_vector_type(8))) short bf16x8_t;
typedef __attribute__((ext_vector_type(4))) float f32x4_t;

__device__ __forceinline__ float b2f(unsigned short u) {
  union { unsigned u; float f; } cv; cv.u = (unsigned)u << 16; return cv.f;
}
__device__ __forceinline__ unsigned short f2b(float f) {   // RNE, finite
  union { float f; unsigned u; } cv; cv.f = f;
  return (unsigned short)((cv.u + 0x7FFFu + ((cv.u >> 16) & 1u)) >> 16);
}
__device__ __forceinline__ float ldmix(const void* p, size_t i, int f32) {
  return f32 ? ((const float*)p)[i] : b2f(((const unsigned short*)p)[i]);
}
// 8 bf16 from LDS via two b64 reads (rows only 8B-aligned at VST=212)
__device__ __forceinline__ bf16x8_t ld8(const unsigned short* p) {
  short4 a = *(const short4*)p;
  short4 b = *(const short4*)(p + 4);
  bf16x8_t v = {a.x, a.y, a.z, a.w, b.x, b.y, b.z, b.w};
  return v;
}
// async global->LDS, 16B per lane; LDS dest = s + lane*16 (wave-uniform base)
__device__ __forceinline__ void gload16(const unsigned short* g,
                                        unsigned short* s) {
  __builtin_amdgcn_global_load_lds(
      (const __attribute__((address_space(1))) void*)g,
      (__attribute__((address_space(3))) void*)s, 16, 0, 0);
}

// ---------------------------------------------------------------------------
__global__ void detect_kernel(const void* x, int* flag) {
  __shared__ int cnt;
  if (threadIdx.x == 0) cnt = 0;
  __syncthreads();
  const unsigned short* u = (const unsigned short*)x;
  int wild = 0;
  for (int i = threadIdx.x; i < 4096; i += 256) {
    int e = (u[i] >> 7) & 0xFF;
    wild += (e >= 140);
  }
  atomicAdd(&cnt, wild);
  __syncthreads();
  if (threadIdx.x == 0) *flag = (cnt > 100) ? 1 : 0;
}

__global__ void cvt_all(const void* qkv_w, const void* proj_w, const void* proj_b,
                        unsigned short* wb, unsigned short* pw, float* pbf,
                        const int* flag) {
  const int W3 = 3 * CC * CC, W1 = CC * CC;
  int i = blockIdx.x * 256 + threadIdx.x;
  const int f32 = *flag;
  if (i < W3) {
    wb[i] = f32 ? f2b(((const float*)qkv_w)[i]) : ((const unsigned short*)qkv_w)[i];
  } else if (i < W3 + W1) {
    int j = i - W3;
    pw[j] = f32 ? f2b(((const float*)proj_w)[j]) : ((const unsigned short*)proj_w)[j];
  } else if (i < W3 + W1 + CC) {
    int j = i - W3 - W1;
    pbf[j] = ldmix(proj_b, j, f32);
  }
}

__global__ void cvt_x(const void* __restrict__ x, size_t elem_off,
                      unsigned short* __restrict__ xb, int n8,
                      const int* __restrict__ flag) {
  const int i = blockIdx.x * 256 + threadIdx.x;
  if (i >= n8) return;
  const size_t src = elem_off + (size_t)i * 8;
  bf16x8_t v;
  if (*flag) {
    const float* xp = (const float*)x + src;
    float4 u0 = *(const float4*)xp;
    float4 u1 = *(const float4*)(xp + 4);
    v = bf16x8_t{(short)f2b(u0.x), (short)f2b(u0.y), (short)f2b(u0.z),
                 (short)f2b(u0.w), (short)f2b(u1.x), (short)f2b(u1.y),
                 (short)f2b(u1.z), (short)f2b(u1.w)};
  } else {
    v = *(const bf16x8_t*)((const unsigned short*)x + src);
  }
  *(bf16x8_t*)(xb + (size_t)i * 8) = v;
}

// ---------------------------------------------------------------------------
// qkv_gemm: 128x128 MFMA GEMM, counted-vmcnt double-buffered staging with
// kg XOR swizzle, LDS-coalesced epilogue. XCD-grouped 1-D grid (18 col-tiles).
// ---------------------------------------------------------------------------
__global__ __launch_bounds__(256, 4) void qkv_gemm(
    const unsigned short* __restrict__ xb,
    const unsigned short* __restrict__ wb,
    unsigned short* __restrict__ qkvc, int Mc, int bc, int nRow) {
  const int xcd = blockIdx.x & 7;
  const int seq = blockIdx.x >> 3;
  const int colt = seq % 18;
  const int rowt = (seq / 18) * 8 + xcd;
  if (rowt >= nRow) return;
  const int m0 = rowt * 128;
  const int n0 = colt * 128;

  // staging: As = lds[0..8191] (2x4096 dbuf), Bs = lds[8192..16383]
  // epilogue: lds reused as C tile [128][130] u16 (16640 u16)
  __shared__ unsigned short lds[16640];
  const int lane = threadIdx.x & 63;
  const int wave = threadIdx.x >> 6;
  const int l16  = lane & 15;
  const int quad = lane >> 4;
  const int wm = wave >> 1, wn = wave & 1;

  // stager slot (lane&3) at row (lane>>2) holds logical k-chunk
  // (lane&3)^((lane>>3)&3): pre-swizzled global source, linear LDS dest.
  const int rS   = wave * 16 + (lane >> 2);
  const int koff = ((lane & 3) ^ ((lane >> 3) & 3)) * 8;
  int grA0 = m0 + rS;       if (grA0 >= Mc) grA0 = Mc - 1;
  int grA1 = m0 + rS + 64;  if (grA1 >= Mc) grA1 = Mc - 1;
  const unsigned short* gA0 = xb + (size_t)grA0 * CC + koff;
  const unsigned short* gA1 = xb + (size_t)grA1 * CC + koff;
  const unsigned short* gB0 = wb + (size_t)(n0 + rS) * CC + koff;
  const unsigned short* gB1 = wb + (size_t)(n0 + rS + 64) * CC + koff;
  unsigned short* const sA0 = lds + wave * 512;
  unsigned short* const sA1 = lds + 2048 + wave * 512;
  unsigned short* const sB0 = lds + 8192 + wave * 512;
  unsigned short* const sB1 = lds + 8192 + 2048 + wave * 512;

  // reader: logical k-chunk quad is at slot quad^((l16>>1)&3)
  const int kgs = (quad ^ ((l16 >> 1) & 3)) * 8;

  // prologue: stage kt=0 into buffer 0
  gload16(gA0, sA0); gload16(gA1, sA1);
  gload16(gB0, sB0); gload16(gB1, sB1);
  gA0 += 32; gA1 += 32; gB0 += 32; gB1 += 32;

  f32x4_t acc[4][4] = {};
  #pragma unroll 2
  for (int kt = 0; kt < 24; kt++) {
    const int ro = (kt & 1) << 12;   // read-buffer u16 offset
    const int so = ro ^ 4096;        // stage-buffer u16 offset
    if (kt < 23) {                   // issue next tile, keep 4 loads in flight
      gload16(gA0, sA0 + so); gload16(gA1, sA1 + so);
      gload16(gB0, sB0 + so); gload16(gB1, sB1 + so);
      gA0 += 32; gA1 += 32; gB0 += 32; gB1 += 32;
      asm volatile("s_waitcnt vmcnt(4)" ::: "memory");   // cur tile landed
    } else {
      asm volatile("s_waitcnt vmcnt(0)" ::: "memory");
    }
    __builtin_amdgcn_s_barrier();    // B1: cur buffer fully written
    bf16x8_t afr[4], bfr[4];
    #pragma unroll
    for (int r = 0; r < 4; r++)
      afr[r] = *(const bf16x8_t*)&lds[ro + (wm * 4 + r) * 512 + l16 * 32 + kgs];
    #pragma unroll
    for (int c = 0; c < 4; c++)
      bfr[c] = *(const bf16x8_t*)&lds[8192 + ro + (wn * 4 + c) * 512 + l16 * 32 + kgs];
    asm volatile("s_waitcnt lgkmcnt(0)" ::: "memory");   // reads retired
    __builtin_amdgcn_s_barrier();    // B2: buffer reusable next iteration
    #pragma unroll
    for (int r = 0; r < 4; r++)
      #pragma unroll
      for (int c = 0; c < 4; c++)
        acc[r][c] = __builtin_amdgcn_mfma_f32_16x16x32_bf16(afr[r], bfr[c],
                                                            acc[r][c], 0, 0, 0);
  }

  // ---- epilogue: C -> LDS [128][130] u16, then 128B-run coalesced stores
  #pragma unroll
  for (int c = 0; c < 4; c++)
    #pragma unroll
    for (int r = 0; r < 4; r++)
      #pragma unroll
      for (int i = 0; i < 4; i++)
        lds[(wm * 64 + r * 16 + quad * 4 + i) * 130 + wn * 64 + c * 16 + l16] =
            f2b(acc[r][c][i]);
  __syncthreads();
  {
    const int row = threadIdx.x >> 1;      // 0..127
    const int seg = threadIdx.x & 1;       // 0..1 (64-col head segment)
    const int m = m0 + row;
    if (m < Mc) {
      const int col0 = n0 + seg * 64;
      const int s = col0 / CC;
      const int rem = col0 - s * CC;
      const int hc = rem >> 6;
      const int bb2 = m / NN, n = m - bb2 * NN;
      unsigned short* dst =
          qkvc + ((((size_t)s * bc + bb2) * HH + hc) * NN + n) * DD;
      const unsigned short* srcr = lds + row * 130 + seg * 64;
      #pragma unroll
      for (int j = 0; j < 8; j++) {
        uint4 v;
        v.x = *(const unsigned*)(srcr + j * 8 + 0);
        v.y = *(const unsigned*)(srcr + j * 8 + 2);
        v.z = *(const unsigned*)(srcr + j * 8 + 4);
        v.w = *(const unsigned*)(srcr + j * 8 + 6);
        *(uint4*)(dst + j * 8) = v;
      }
    }
  }
}

// ---------------------------------------------------------------------------
// proj_gemm: 128x128 MFMA GEMM, same K-loop (swizzled), LDS-coalesced
// epilogue with bias + dual-dtype store (two passes, f32 LDS).
// ---------------------------------------------------------------------------
__global__ __launch_bounds__(256, 4) void proj_gemm(
    const unsigned short* __restrict__ Yc,
    const unsigned short* __restrict__ pw,
    const float* __restrict__ pbf,
    void* __restrict__ out, size_t out_off, int Mc, int nRow,
    const int* __restrict__ flag) {
  const int xcd = blockIdx.x & 7;
  const int seq = blockIdx.x >> 3;
  const int colt = seq % 6;
  const int rowt = (seq / 6) * 8 + xcd;
  if (rowt >= nRow) return;
  const int m0 = rowt * 128;
  const int n0 = colt * 128;

  // staging 16384 u16; epilogue reuses as float [128][67] = 8576 f32
  __shared__ unsigned short lds[17152];
  const int lane = threadIdx.x & 63;
  const int wave = threadIdx.x >> 6;
  const int l16  = lane & 15;
  const int quad = lane >> 4;
  const int wm = wave >> 1, wn = wave & 1;

  const int rS   = wave * 16 + (lane >> 2);
  const int koff = ((lane & 3) ^ ((lane >> 3) & 3)) * 8;
  int grA0 = m0 + rS;       if (grA0 >= Mc) grA0 = Mc - 1;
  int grA1 = m0 + rS + 64;  if (grA1 >= Mc) grA1 = Mc - 1;
  const unsigned short* gA0 = Yc + (size_t)grA0 * CC + koff;
  const unsigned short* gA1 = Yc + (size_t)grA1 * CC + koff;
  const unsigned short* gB0 = pw + (size_t)(n0 + rS) * CC + koff;
  const unsigned short* gB1 = pw + (size_t)(n0 + rS + 64) * CC + koff;
  unsigned short* const sA0 = lds + wave * 512;
  unsigned short* const sA1 = lds + 2048 + wave * 512;
  unsigned short* const sB0 = lds + 8192 + wave * 512;
  unsigned short* const sB1 = lds + 8192 + 2048 + wave * 512;

  const int kgs = (quad ^ ((l16 >> 1) & 3)) * 8;

  gload16(gA0, sA0); gload16(gA1, sA1);
  gload16(gB0, sB0); gload16(gB1, sB1);
  gA0 += 32; gA1 += 32; gB0 += 32; gB1 += 32;

  f32x4_t acc[4][4] = {};
  #pragma unroll 2
  for (int kt = 0; kt < 24; kt++) {
    const int ro = (kt & 1) << 12;
    const int so = ro ^ 4096;
    if (kt < 23) {
      gload16(gA0, sA0 + so); gload16(gA1, sA1 + so);
      gload16(gB0, sB0 + so); gload16(gB1, sB1 + so);
      gA0 += 32; gA1 += 32; gB0 += 32; gB1 += 32;
      asm volatile("s_waitcnt vmcnt(4)" ::: "memory");
    } else {
      asm volatile("s_waitcnt vmcnt(0)" ::: "memory");
    }
    __builtin_amdgcn_s_barrier();
    bf16x8_t afr[4], bfr[4];
    #pragma unroll
    for (int r = 0; r < 4; r++)
      afr[r] = *(const bf16x8_t*)&lds[ro + (wm * 4 + r) * 512 + l16 * 32 + kgs];
    #pragma unroll
    for (int c = 0; c < 4; c++)
      bfr[c] = *(const bf16x8_t*)&lds[8192 + ro + (wn * 4 + c) * 512 + l16 * 32 + kgs];
    asm volatile("s_waitcnt lgkmcnt(0)" ::: "memory");
    __builtin_amdgcn_s_barrier();
    #pragma unroll
    for (int r = 0; r < 4; r++)
      #pragma unroll
      for (int c = 0; c < 4; c++)
        acc[r][c] = __builtin_amdgcn_mfma_f32_16x16x32_bf16(afr[r], bfr[c],
                                                            acc[r][c], 0, 0, 0);
  }

  // ---- epilogue: two passes (col halves), f32 LDS [128][67], full-line stores
  const int f32o = *flag;
  float* Cf = (float*)lds;
  #pragma unroll
  for (int p = 0; p < 2; p++) {
    __syncthreads();
    if (wn == p) {
      #pragma unroll
      for (int c = 0; c < 4; c++) {
        const float bv = pbf[n0 + wn * 64 + c * 16 + l16];
        #pragma unroll
        for (int r = 0; r < 4; r++)
          #pragma unroll
          for (int i = 0; i < 4; i++)
            Cf[(wm * 64 + r * 16 + quad * 4 + i) * 67 + c * 16 + l16] =
                acc[r][c][i] + bv;
      }
    }
    __syncthreads();
    const int row = threadIdx.x >> 1;
    const int part = threadIdx.x & 1;
    const int m = m0 + row;
    if (m < Mc) {
      const float* srcr = Cf + row * 67 + part * 32;
      const size_t ob = out_off + (size_t)m * CC + n0 + p * 64 + part * 32;
      if (f32o) {
        float* dst = (float*)out + ob;
        #pragma unroll
        for (int j = 0; j < 8; j++) {
          float4 v = {srcr[j * 4], srcr[j * 4 + 1], srcr[j * 4 + 2],
                      srcr[j * 4 + 3]};
          *(float4*)(dst + j * 4) = v;
        }
      } else {
        unsigned short* dst = (unsigned short*)out + ob;
        #pragma unroll
        for (int j = 0; j < 4; j++) {
          uint4 v;
          v.x = (unsigned)f2b(srcr[j * 8 + 0]) | ((unsigned)f2b(srcr[j * 8 + 1]) << 16);
          v.y = (unsigned)f2b(srcr[j * 8 + 2]) | ((unsigned)f2b(srcr[j * 8 + 3]) << 16);
          v.z = (unsigned)f2b(srcr[j * 8 + 4]) | ((unsigned)f2b(srcr[j * 8 + 5]) << 16);
          v.w = (unsigned)f2b(srcr[j * 8 + 6]) | ((unsigned)f2b(srcr[j * 8 + 7]) << 16);
          *(uint4*)(dst + j * 8) = v;
        }
      }
    }
  }
}

// ---------------------------------------------------------------------------
// MFMA attention (unchanged R7/R8 structure).
// ---------------------------------------------------------------------------
__global__ __launch_bounds__(256, 3) void attn_kernel(
    const unsigned short* __restrict__ qkvc, int bc,
    unsigned short* __restrict__ Yc) {
  const int bh = blockIdx.x;
  const int bb = bh / HH;
  const int h  = bh % HH;
  const size_t mat = (size_t)bc * HH * NN * DD;
  const unsigned short* q = qkvc + ((size_t)bb * HH + h) * NN * DD;
  const unsigned short* k = q + mat;
  const unsigned short* v = q + 2 * mat;

  __shared__ unsigned short Vt[DD * VST];
  __shared__ unsigned short Pl[4][16 * VST];

  const int lane = threadIdx.x & 63;
  const int wave = threadIdx.x >> 6;
  const int l16  = lane & 15;
  const int quad = lane >> 4;

  #pragma unroll
  for (int it = 0; it < 53; it++) {
    const int key = it * 4 + wave;
    unsigned short val = (key < NN) ? v[(size_t)key * DD + lane]
                                    : (unsigned short)0;
    Vt[lane * VST + key] = val;
  }
  __syncthreads();

  unsigned short* Pw = &Pl[wave][0];

  for (int it = 0; it < 4; it++) {
    const int si = it * 4 + wave;
    if (si >= 13) break;
    const int q0 = si * 16;

    int qrow = q0 + l16; if (qrow >= NN) qrow = NN - 1;
    const unsigned short* qp = q + (size_t)qrow * DD + quad * 8;
    const bf16x8_t aq0 = *(const bf16x8_t*)qp;
    const bf16x8_t aq1 = *(const bf16x8_t*)(qp + 32);

    f32x4_t sc[13];
    #pragma unroll
    for (int ct = 0; ct < 13; ct++) {
      int key = ct * 16 + l16; if (key >= NN) key = NN - 1;
      const unsigned short* kp = k + (size_t)key * DD + quad * 8;
      const bf16x8_t b0 = *(const bf16x8_t*)kp;
      const bf16x8_t b1 = *(const bf16x8_t*)(kp + 32);
      f32x4_t t = {0.f, 0.f, 0.f, 0.f};
      t = __builtin_amdgcn_mfma_f32_16x16x32_bf16(aq0, b0, t, 0, 0, 0);
      t = __builtin_amdgcn_mfma_f32_16x16x32_bf16(aq1, b1, t, 0, 0, 0);
      sc[ct] = t;
    }

    float inv_l[4];
    #pragma unroll
    for (int i = 0; i < 4; i++) {
      float m = -1e30f;
      #pragma unroll
      for (int ct = 0; ct < 13; ct++)
        if (ct < 12 || l16 < 5) m = fmaxf(m, sc[ct][i] * SCALE_F);
      #pragma unroll
      for (int d = 1; d < 16; d <<= 1) m = fmaxf(m, __shfl_xor(m, d, 64));
      float s = 0.f;
      #pragma unroll
      for (int ct = 0; ct < 13; ct++) {
        const float p = (ct < 12 || l16 < 5) ? __expf(sc[ct][i] * SCALE_F - m)
                                             : 0.f;
        sc[ct][i] = p;
        s += p;
      }
      #pragma unroll
      for (int d = 1; d < 16; d <<= 1) s += __shfl_xor(s, d, 64);
      inv_l[i] = 1.0f / s;
    }

    #pragma unroll
    for (int i = 0; i < 4; i++) {
      const int ro = (quad * 4 + i) * VST;
      #pragma unroll
      for (int ct = 0; ct < 13; ct++)
        Pw[ro + ct * 16 + l16] = f2b(sc[ct][i]);
    }

    f32x4_t oc[4] = {};
    #pragma unroll
    for (int ks = 0; ks < 6; ks++) {
      const bf16x8_t ap = ld8(&Pw[l16 * VST + ks * 32 + quad * 8]);
      #pragma unroll
      for (int dt = 0; dt < 4; dt++) {
        const bf16x8_t bv = ld8(&Vt[(dt * 16 + l16) * VST + ks * 32 + quad * 8]);
        oc[dt] = __builtin_amdgcn_mfma_f32_16x16x32_bf16(ap, bv, oc[dt], 0, 0, 0);
      }
    }
    {
      const bf16x8_t zz = {};
      bf16x8_t ap = zz;
      if (quad < 2) ap = ld8(&Pw[l16 * VST + 192 + quad * 8]);
      #pragma unroll
      for (int dt = 0; dt < 4; dt++) {
        bf16x8_t bv = zz;
        if (quad < 2) bv = ld8(&Vt[(dt * 16 + l16) * VST + 192 + quad * 8]);
        oc[dt] = __builtin_amdgcn_mfma_f32_16x16x32_bf16(ap, bv, oc[dt], 0, 0, 0);
      }
    }

    #pragma unroll
    for (int i = 0; i < 4; i++) {
      const int n = q0 + quad * 4 + i;
      if (n < NN) {
        unsigned short* yp = Yc + ((size_t)bb * NN + n) * CC + h * DD;
        #pragma unroll
        for (int dt = 0; dt < 4; dt++)
          yp[dt * 16 + l16] = f2b(oc[dt][i] * inv_l[i]);
      }
    }
  }
}

// ---------------------------------------------------------------------------
// Top-k path (fp32-exact).
// ---------------------------------------------------------------------------
__global__ __launch_bounds__(256, 4) void qcls_kernel(
    const void* __restrict__ x, const void* __restrict__ qkv_w,
    float* __restrict__ qc, const int* __restrict__ flag) {
  const int idx = blockIdx.x * 4 + (threadIdx.x >> 6);
  if (idx >= BB * CC) return;
  const int b = idx / CC, i = idx - b * CC;
  const int lane = threadIdx.x & 63;
  const int f32 = *flag;
  const size_t xr = (size_t)b * NN * CC;
  const size_t wr = (size_t)i * CC;
  float p = 0.f;
  #pragma unroll
  for (int j = 0; j < 12; j++)
    p += ldmix(x, xr + j * 64 + lane, f32) * ldmix(qkv_w, wr + j * 64 + lane, f32);
  #pragma unroll
  for (int m = 32; m; m >>= 1) p += __shfl_xor(p, m, 64);
  if (lane == 0) qc[(size_t)b * CC + i] = p;
}

// gmat: R10 form — grid (b, h), 768 blocks, 3 cols/thread.
__global__ __launch_bounds__(256, 4) void gmat_kernel(
    const void* __restrict__ qkv_w, const float* __restrict__ qc,
    float* __restrict__ g, const int* __restrict__ flag) {
  const int b = blockIdx.x, h = blockIdx.y;
  const int f32 = *flag;
  __shared__ float qh[DD];
  if (threadIdx.x < DD) qh[threadIdx.x] = qc[(size_t)b * CC + h * DD + threadIdx.x];
  __syncthreads();
  const int c0 = threadIdx.x, c1 = c0 + 256, c2 = c1 + 256;
  float a0 = 0.f, a1 = 0.f, a2 = 0.f;
  for (int d = 0; d < DD; d++) {
    const size_t ro = (size_t)(CC + h * DD + d) * CC;
    const float qv = qh[d];
    a0 += ldmix(qkv_w, ro + c0, f32) * qv;
    a1 += ldmix(qkv_w, ro + c1, f32) * qv;
    a2 += ldmix(qkv_w, ro + c2, f32) * qv;
  }
  float* gb = g + ((size_t)b * HH + h) * CC;
  gb[c0] = a0; gb[c1] = a1; gb[c2] = a2;
}

__global__ __launch_bounds__(256, 4) void score_kernel(
    const void* __restrict__ x, const float* __restrict__ g,
    float* __restrict__ wscore, const int* __restrict__ flag) {
  const int idx = blockIdx.x * 4 + (threadIdx.x >> 6);
  if (idx >= BB * NN) return;
  const int b = idx / NN, n = idx - b * NN;
  const int lane = threadIdx.x & 63;
  const int f32 = *flag;
  const size_t xr = ((size_t)b * NN + n) * CC;
  float xv[12];
  #pragma unroll
  for (int j = 0; j < 12; j++) xv[j] = ldmix(x, xr + j * 64 + lane, f32);
  const float* gb = g + (size_t)b * HH * CC;
  float acc = 0.f;
  #pragma unroll
  for (int h = 0; h < HH; h++) {
    const float* gh = gb + (size_t)h * CC;
    float p = 0.f;
    #pragma unroll
    for (int j = 0; j < 12; j++) p += xv[j] * gh[j * 64 + lane];
    #pragma unroll
    for (int m = 32; m; m >>= 1) p += __shfl_xor(p, m, 64);
    acc += fabsf(p);
  }
  if (lane == 0) wscore[(size_t)b * NN + n] = acc;
}

__global__ __launch_bounds__(256, 4) void rank_kernel(
    const float* __restrict__ wscore, void* __restrict__ out,
    const int* __restrict__ flag) {
  const int b = blockIdx.x;
  const int f32 = *flag;
  __shared__ float wgt[NN];
  __shared__ int   rank[NN];
  if (threadIdx.x < NN) wgt[threadIdx.x] = wscore[(size_t)b * NN + threadIdx.x];
  __syncthreads();
  const int n = threadIdx.x;
  if (n < NN) {
    float wi = wgt[n];
    int rk = 0;
    for (int j = 0; j < NN; j++) {
      float wj = wgt[j];
      rk += (wj > wi) || (wj == wi && j < n);
    }
    rank[n] = rk;
  }
  __syncthreads();
  if (n < NN && rank[n] < KEEP) {
    int pos = 0;
    for (int j = 0; j < n; j++) pos += (rank[j] < KEEP);
    const size_t oi = OUT0_ELEMS + (size_t)b * KEEP + pos;
    if (f32) ((float*)out)[oi] = (float)n;
    else ((unsigned short*)out)[oi] = f2b((float)n);
  }
}

// ---------------------------------------------------------------------------
extern "C" void kernel_launch(void* const* d_in, const int* in_sizes, int n_in,
                              void* d_out, int out_size, void* d_ws, size_t ws_size,
                              hipStream_t stream) {
  const void* x      = d_in[0];
  const void* qkv_w  = d_in[1];
  const void* proj_w = d_in[2];
  const void* proj_b = d_in[3];

  char* wsb = (char*)d_ws;
  int* flag = (int*)wsb;
  unsigned short* wb  = (unsigned short*)(wsb + 256);
  unsigned short* pw  = (unsigned short*)(wsb + 256 + 3538944);
  float* pbf    = (float*)(wsb + 256 + 3538944 + 1179648);
  float* qc     = (float*)(wsb + 256 + 3538944 + 1179648 + 4096);
  float* g      = qc + (size_t)BB * CC;
  float* wscore = g + (size_t)BB * HH * CC;
  const size_t fixed = 256 + 3538944 + 1179648 + 4096 + 196608 + 2359296 + 51200;
  char* chunk = wsb + fixed;

  const size_t per_batch = (size_t)NN * CC * 2
                         + 3ull * HH * NN * DD * 2
                         + (size_t)NN * CC * 2;
  int Bc = BB;
  while (Bc > 1 && fixed + (size_t)Bc * per_batch > ws_size) Bc >>= 1;

  unsigned short* xb   = (unsigned short*)chunk;
  unsigned short* qkvc = xb + (size_t)Bc * NN * CC;
  unsigned short* Yc   = qkvc + 3ull * Bc * HH * NN * DD;

  detect_kernel<<<1, 256, 0, stream>>>(x, flag);
  const int cvt_n = 3 * CC * CC + CC * CC + CC;
  cvt_all<<<(cvt_n + 255) / 256, 256, 0, stream>>>(qkv_w, proj_w, proj_b,
                                                   wb, pw, pbf, flag);

  qcls_kernel<<<(BB * CC + 3) / 4, 256, 0, stream>>>(x, qkv_w, qc, flag);
  gmat_kernel<<<dim3(BB, HH), 256, 0, stream>>>(qkv_w, qc, g, flag);
  score_kernel<<<(BB * NN + 3) / 4, 256, 0, stream>>>(x, g, wscore, flag);
  rank_kernel<<<BB, 256, 0, stream>>>(wscore, d_out, flag);

  const int nChunks = (BB + Bc - 1) / Bc;
  for (int cb = 0; cb < nChunks; cb++) {
    const int b0 = cb * Bc;
    const int bc = (BB - b0 < Bc) ? (BB - b0) : Bc;
    const int Mc = bc * NN;
    const int n8 = Mc * CC / 8;
    cvt_x<<<(n8 + 255) / 256, 256, 0, stream>>>(
        x, (size_t)b0 * NN * CC, xb, n8, flag);
    const int nRowQ = (Mc + 127) / 128;
    const int gridQ = 8 * 18 * ((nRowQ + 7) / 8);
    qkv_gemm<<<gridQ, 256, 0, stream>>>(xb, wb, qkvc, Mc, bc, nRowQ);
    attn_kernel<<<dim3(bc * HH), 256, 0, stream>>>(qkvc, bc, Yc);
    const int gridP = 8 * 6 * ((nRowQ + 7) / 8);
    proj_gemm<<<gridP, 256, 0, stream>>>(
        Yc, pw, pbf, d_out, (size_t)b0 * NN * CC, Mc, nRowQ, flag);
  }
}